// Round 1
// baseline (1532.748 us; speedup 1.0000x reference)
//
#include <hip/hip_runtime.h>
#include <hip/hip_bf16.h>
#include <math.h>

#define BDIM 4
#define VDIM 8
#define NDIM 256
#define CDIM 768
#define HDIM 12
#define DHE  64
#define C3   (3*CDIM)
#define ROWS (BDIM*VDIM*NDIM)

// ---------------------------------------------------------------------------
// GEMM: out[rows x ncols] = A[rows x K] @ W[ncols x K]^T + bias
// EPI==0: plain bias epilogue (QKV projection)
// EPI==1: bias + has_ctx select against feats (output projection)
// 64x64 tile, 256 threads, each thread 4x4. LDS tiles stored transposed
// (As[kk][row]) with row-stride 68 so fragment reads are aligned float4
// and worst bank aliasing is 2-way (free on gfx950).
// ---------------------------------------------------------------------------
template<int EPI>
__global__ __launch_bounds__(256) void gemm_kernel(
    const float* __restrict__ A, const float* __restrict__ W,
    const float* __restrict__ bias, float* __restrict__ out,
    int K, int ncols,
    const float* __restrict__ feats, const int* __restrict__ is_ref)
{
    __shared__ float As[16][68];
    __shared__ float Ws[16][68];
    const int t   = threadIdx.x;
    const int tx  = t & 15;
    const int ty  = t >> 4;
    const int row0 = blockIdx.y * 64;
    const int col0 = blockIdx.x * 64;
    const int ar = t >> 2;          // 0..63: tile row this thread stages
    const int ak = (t & 3) << 2;    // 0,4,8,12: k-offset (float4)

    float acc[4][4];
    #pragma unroll
    for (int i = 0; i < 4; i++)
        #pragma unroll
        for (int j = 0; j < 4; j++) acc[i][j] = 0.f;

    for (int k0 = 0; k0 < K; k0 += 16) {
        float4 av = *(const float4*)(A + (size_t)(row0 + ar) * K + k0 + ak);
        float4 wv = *(const float4*)(W + (size_t)(col0 + ar) * K + k0 + ak);
        As[ak + 0][ar] = av.x; As[ak + 1][ar] = av.y;
        As[ak + 2][ar] = av.z; As[ak + 3][ar] = av.w;
        Ws[ak + 0][ar] = wv.x; Ws[ak + 1][ar] = wv.y;
        Ws[ak + 2][ar] = wv.z; Ws[ak + 3][ar] = wv.w;
        __syncthreads();
        #pragma unroll
        for (int kk = 0; kk < 16; kk++) {
            float4 a4 = *(const float4*)&As[kk][ty << 2];
            float4 b4 = *(const float4*)&Ws[kk][tx << 2];
            float aa[4] = {a4.x, a4.y, a4.z, a4.w};
            float bb[4] = {b4.x, b4.y, b4.z, b4.w};
            #pragma unroll
            for (int i = 0; i < 4; i++)
                #pragma unroll
                for (int j = 0; j < 4; j++) acc[i][j] += aa[i] * bb[j];
        }
        __syncthreads();
    }

    float4 bv = *(const float4*)(bias + col0 + (tx << 2));
    bool has = true;
    if (EPI == 1) {
        // all 64 rows of this tile belong to one (b, v): N=256 is a multiple of 64
        const int bidx = row0 / (VDIM * NDIM);
        const int vidx = (row0 / NDIM) % VDIM;
        const int my = is_ref[bidx * VDIM + vidx];
        bool any = false;
        #pragma unroll
        for (int w = 0; w < VDIM; w++) any = any || (is_ref[bidx * VDIM + w] != my);
        has = any;
    }
    #pragma unroll
    for (int i = 0; i < 4; i++) {
        const int r = row0 + (ty << 2) + i;
        float4 o;
        o.x = acc[i][0] + bv.x;
        o.y = acc[i][1] + bv.y;
        o.z = acc[i][2] + bv.z;
        o.w = acc[i][3] + bv.w;
        if (EPI == 1 && !has) {
            o = *(const float4*)(feats + (size_t)r * CDIM + col0 + (tx << 2));
        }
        *(float4*)(out + (size_t)r * ncols + col0 + (tx << 2)) = o;
    }
}

// ---------------------------------------------------------------------------
// Flash-style masked cross-view attention.
// grid = (V, H, B), block = 256 threads (one thread per query row n).
// Keys/values for allowed view-blocks are staged 128 rows at a time in LDS.
// Online softmax in 8-key chunks. Masked views skipped entirely (exact:
// exp(NEG - max) underflows to 0 in the reference softmax).
// ---------------------------------------------------------------------------
__global__ __launch_bounds__(256) void attn_kernel(
    const float* __restrict__ qkv, const int* __restrict__ is_ref,
    float* __restrict__ ctx)
{
    const int v = blockIdx.x, h = blockIdx.y, b = blockIdx.z;
    const int n = threadIdx.x;

    __shared__ float kk_s[128][64];
    __shared__ float vv_s[128][64];

    const int my_ref = is_ref[b * VDIM + v];

    // load & pre-scale q row (1/sqrt(64) = 0.125)
    float q[64];
    const float* qrow = qkv + ((size_t)((b * VDIM + v) * NDIM) + n) * C3 + h * DHE;
    #pragma unroll
    for (int d4 = 0; d4 < 16; d4++) {
        float4 t4 = *(const float4*)(qrow + d4 * 4);
        q[d4 * 4 + 0] = t4.x * 0.125f;
        q[d4 * 4 + 1] = t4.y * 0.125f;
        q[d4 * 4 + 2] = t4.z * 0.125f;
        q[d4 * 4 + 3] = t4.w * 0.125f;
    }

    float m_run = -1e30f, l_run = 0.f;
    float acc[64];
    #pragma unroll
    for (int d = 0; d < 64; d++) acc[d] = 0.f;

    for (int w = 0; w < VDIM; w++) {
        if (!((is_ref[b * VDIM + w] != 0) ^ (my_ref != 0))) continue;  // block-uniform
        for (int m0 = 0; m0 < NDIM; m0 += 128) {
            // stage 128 keys + values: 2048 float4 each, 8 per thread
            #pragma unroll
            for (int i = 0; i < 8; i++) {
                const int idx = threadIdx.x + 256 * i;
                const int mi = idx >> 4, d4 = idx & 15;
                const float* base =
                    qkv + ((size_t)((b * VDIM + w) * NDIM) + m0 + mi) * C3 + h * DHE + d4 * 4;
                *(float4*)&kk_s[mi][d4 * 4] = *(const float4*)(base + CDIM);
                *(float4*)&vv_s[mi][d4 * 4] = *(const float4*)(base + 2 * CDIM);
            }
            __syncthreads();

            for (int mi0 = 0; mi0 < 128; mi0 += 8) {
                float s[8];
                #pragma unroll
                for (int jj = 0; jj < 8; jj++) {
                    float s0 = 0.f, s1 = 0.f, s2 = 0.f, s3 = 0.f;
                    #pragma unroll
                    for (int d4 = 0; d4 < 16; d4++) {
                        float4 kv = *(const float4*)&kk_s[mi0 + jj][d4 * 4];
                        s0 += q[d4 * 4 + 0] * kv.x;
                        s1 += q[d4 * 4 + 1] * kv.y;
                        s2 += q[d4 * 4 + 2] * kv.z;
                        s3 += q[d4 * 4 + 3] * kv.w;
                    }
                    s[jj] = (s0 + s1) + (s2 + s3);
                }
                float cmax = s[0];
                #pragma unroll
                for (int jj = 1; jj < 8; jj++) cmax = fmaxf(cmax, s[jj]);
                const float m_new = fmaxf(m_run, cmax);
                const float scale = __expf(m_run - m_new);
                float p[8], psum = 0.f;
                #pragma unroll
                for (int jj = 0; jj < 8; jj++) { p[jj] = __expf(s[jj] - m_new); psum += p[jj]; }
                l_run = l_run * scale + psum;
                m_run = m_new;
                #pragma unroll
                for (int d4 = 0; d4 < 16; d4++) {
                    float x0 = acc[d4 * 4 + 0] * scale;
                    float x1 = acc[d4 * 4 + 1] * scale;
                    float x2 = acc[d4 * 4 + 2] * scale;
                    float x3 = acc[d4 * 4 + 3] * scale;
                    #pragma unroll
                    for (int jj = 0; jj < 8; jj++) {
                        float4 vv = *(const float4*)&vv_s[mi0 + jj][d4 * 4];
                        x0 += p[jj] * vv.x;
                        x1 += p[jj] * vv.y;
                        x2 += p[jj] * vv.z;
                        x3 += p[jj] * vv.w;
                    }
                    acc[d4 * 4 + 0] = x0;
                    acc[d4 * 4 + 1] = x1;
                    acc[d4 * 4 + 2] = x2;
                    acc[d4 * 4 + 3] = x3;
                }
            }
            __syncthreads();
        }
    }

    const float inv = (l_run > 0.f) ? 1.f / l_run : 0.f;
    float* crow = ctx + ((size_t)((b * VDIM + v) * NDIM) + n) * CDIM + h * DHE;
    #pragma unroll
    for (int d4 = 0; d4 < 16; d4++) {
        float4 o;
        o.x = acc[d4 * 4 + 0] * inv;
        o.y = acc[d4 * 4 + 1] * inv;
        o.z = acc[d4 * 4 + 2] * inv;
        o.w = acc[d4 * 4 + 3] * inv;
        *(float4*)(crow + d4 * 4) = o;
    }
}

extern "C" void kernel_launch(void* const* d_in, const int* in_sizes, int n_in,
                              void* d_out, int out_size, void* d_ws, size_t ws_size,
                              hipStream_t stream) {
    const float* feats = (const float*)d_in[0];
    const int*   is_ref = (const int*)d_in[1];
    const float* w_qkv = (const float*)d_in[2];
    const float* b_qkv = (const float*)d_in[3];
    const float* w_out = (const float*)d_in[4];
    const float* b_out = (const float*)d_in[5];
    float* out = (float*)d_out;

    float* qkv = (float*)d_ws;                       // ROWS x 3C   (75.5 MB)
    float* ctx = qkv + (size_t)ROWS * C3;            // ROWS x C    (25.2 MB)

    dim3 g1(C3 / 64, ROWS / 64);                     // 36 x 128
    gemm_kernel<0><<<g1, 256, 0, stream>>>(feats, w_qkv, b_qkv, qkv, CDIM, C3,
                                           nullptr, nullptr);

    dim3 g2(VDIM, HDIM, BDIM);                       // 8 x 12 x 4 = 384 blocks
    attn_kernel<<<g2, 256, 0, stream>>>(qkv, is_ref, ctx);

    dim3 g3(CDIM / 64, ROWS / 64);                   // 12 x 128
    gemm_kernel<1><<<g3, 256, 0, stream>>>(ctx, w_out, b_out, out, CDIM, CDIM,
                                           feats, is_ref);
    (void)in_sizes; (void)n_in; (void)out_size; (void)ws_size;
}

// Round 2
// 445.921 us; speedup vs baseline: 3.4373x; 3.4373x over previous
//
#include <hip/hip_runtime.h>
#include <hip/hip_bf16.h>
#include <math.h>

#define BDIM 4
#define VDIM 8
#define NDIM 256
#define CDIM 768
#define HDIM 12
#define DHE  64
#define C3   (3*CDIM)
#define ROWS (BDIM*VDIM*NDIM)

typedef __attribute__((ext_vector_type(8))) short short8;   // 8 bf16 = 4 VGPR
typedef __attribute__((ext_vector_type(4))) float float4v;  // MFMA acc

__device__ inline unsigned short f2bf(float f) {
    unsigned int u = __builtin_bit_cast(unsigned int, f);
    u += 0x7fffu + ((u >> 16) & 1u);   // RNE
    return (unsigned short)(u >> 16);
}

// ---------------------------------------------------------------------------
// fp32 -> bf16 cast, vectorized (n4 = #float4 groups)
// ---------------------------------------------------------------------------
__global__ void cast_bf16_kernel(const float* __restrict__ src,
                                 unsigned short* __restrict__ dst, int n4) {
    int i = blockIdx.x * blockDim.x + threadIdx.x;
    const int stride = gridDim.x * blockDim.x;
    for (; i < n4; i += stride) {
        float4 f = ((const float4*)src)[i];
        ushort4 o;
        o.x = f2bf(f.x); o.y = f2bf(f.y); o.z = f2bf(f.z); o.w = f2bf(f.w);
        ((ushort4*)dst)[i] = o;
    }
}

// ---------------------------------------------------------------------------
// bf16 MFMA GEMM: qkv[8192 x 2304] = feats_b[8192 x 768] @ w_qkv_b[2304 x 768]^T
// + bias (fp32), output bf16. Tile 128x128, BK=32, 4 waves each 64x64.
// LDS k-chunk-major layout [kc][row][8] -> all frag reads are aligned
// ds_read_b128 with only 2-way bank aliasing (free).
// ---------------------------------------------------------------------------
__global__ __launch_bounds__(256) void gemm_qkv_mfma(
    const unsigned short* __restrict__ A,   // [8192][768] bf16
    const unsigned short* __restrict__ W,   // [2304][768] bf16
    const float* __restrict__ bias,
    unsigned short* __restrict__ out)       // [8192][2304] bf16
{
    __shared__ unsigned short As[4][128][8];
    __shared__ unsigned short Ws[4][128][8];
    const int t = threadIdx.x;
    const int wave = t >> 6, lane = t & 63;
    const int m = lane & 15, quad = lane >> 4;
    const int wr = (wave >> 1) * 64, wc = (wave & 1) * 64;
    const int row0 = blockIdx.y * 128, col0 = blockIdx.x * 128;

    float4v acc[4][4] = {};

    for (int k0 = 0; k0 < CDIM; k0 += 32) {
        #pragma unroll
        for (int i = 0; i < 2; i++) {
            const int c = t + 256 * i;          // 0..511
            const int r = c >> 2, ko = (c & 3) << 3;
            *(uint4*)&As[ko >> 3][r][0] =
                *(const uint4*)&A[(size_t)(row0 + r) * CDIM + k0 + ko];
            *(uint4*)&Ws[ko >> 3][r][0] =
                *(const uint4*)&W[(size_t)(col0 + r) * CDIM + k0 + ko];
        }
        __syncthreads();
        short8 a[4], b[4];
        #pragma unroll
        for (int rt = 0; rt < 4; rt++) a[rt] = *(const short8*)&As[quad][wr + rt * 16 + m][0];
        #pragma unroll
        for (int ct = 0; ct < 4; ct++) b[ct] = *(const short8*)&Ws[quad][wc + ct * 16 + m][0];
        #pragma unroll
        for (int rt = 0; rt < 4; rt++)
            #pragma unroll
            for (int ct = 0; ct < 4; ct++)
                acc[rt][ct] = __builtin_amdgcn_mfma_f32_16x16x32_bf16(
                    a[rt], b[ct], acc[rt][ct], 0, 0, 0);
        __syncthreads();
    }

    // epilogue: C layout col=lane&15, row=quad*4+reg
    #pragma unroll
    for (int ct = 0; ct < 4; ct++) {
        const int col = col0 + wc + ct * 16 + m;
        const float bv = bias[col];
        #pragma unroll
        for (int rt = 0; rt < 4; rt++) {
            const size_t row = (size_t)row0 + wr + rt * 16 + quad * 4;
            #pragma unroll
            for (int r = 0; r < 4; r++)
                out[(row + r) * C3 + col] = f2bf(acc[rt][ct][r] + bv);
        }
    }
}

// ---------------------------------------------------------------------------
// MFMA flash attention. grid = (V, H, 2*B), block = 256 (4 waves x 32 rows).
// 64-key chunks; K staged [dimchunk][key][8], V staged transposed
// [keychunk][dim][8]; P round-trips LDS (C-layout -> A-layout, wave-private,
// DS pipe is in-order within a wave so no barrier needed for Ps).
// Softmax in exp2 domain with folded scale c1 = 0.125*log2(e).
// ---------------------------------------------------------------------------
__global__ __launch_bounds__(256) void attn_mfma(
    const unsigned short* __restrict__ qkv,  // [8192][2304] bf16
    const int* __restrict__ is_ref,
    float* __restrict__ ctx)                 // [8192][768] fp32
{
    const int v = blockIdx.x, h = blockIdx.y;
    const int b = blockIdx.z >> 1, half = blockIdx.z & 1;
    const int t = threadIdx.x, wave = t >> 6, lane = t & 63;
    const int m = lane & 15, quad = lane >> 4;
    const int n0 = half * 128 + wave * 32;

    __shared__ unsigned short Ks[8][64][8];
    __shared__ unsigned short Vt[8][64][8];
    __shared__ unsigned short Ps[4][8][32][8];

    const int my_ref = is_ref[b * VDIM + v];
    const float c1 = 0.18033688f;  // 0.125 * log2(e)

    // Q A-frags: A[m=lane&15][k=quad*8+j], two K-steps of 32 over DH=64
    short8 aq[2][2];
    #pragma unroll
    for (int rt = 0; rt < 2; rt++) {
        const size_t row = (size_t)((b * VDIM + v) * NDIM) + n0 + rt * 16 + m;
        #pragma unroll
        for (int ks = 0; ks < 2; ks++)
            aq[rt][ks] = *(const short8*)&qkv[row * C3 + h * DHE + ks * 32 + quad * 8];
    }

    float m_run[2][4], l_run[2][4];
    float4v O[2][4] = {};
    #pragma unroll
    for (int rt = 0; rt < 2; rt++)
        #pragma unroll
        for (int r = 0; r < 4; r++) { m_run[rt][r] = -1e30f; l_run[rt][r] = 0.f; }

    for (int w = 0; w < VDIM; w++) {
        if (((is_ref[b * VDIM + w] != 0) ^ (my_ref != 0)) == 0) continue;
        for (int m0 = 0; m0 < NDIM; m0 += 64) {
            __syncthreads();   // previous chunk's K/V reads complete
            #pragma unroll
            for (int i = 0; i < 2; i++) {
                const int c = t + 256 * i;          // 0..511
                const int key = c >> 3, dc = c & 7;
                const size_t krow = (size_t)((b * VDIM + w) * NDIM) + m0 + key;
                const size_t base = krow * C3 + h * DHE + dc * 8;
                *(uint4*)&Ks[dc][key][0] = *(const uint4*)&qkv[base + CDIM];
                unsigned short vt[8];
                *(uint4*)vt = *(const uint4*)&qkv[base + 2 * CDIM];
                #pragma unroll
                for (int j = 0; j < 8; j++) Vt[key >> 3][dc * 8 + j][key & 7] = vt[j];
            }
            __syncthreads();

            // S = Q @ K^T  (raw, scale folded into exp2 domain)
            float4v S[2][4];
            #pragma unroll
            for (int nt = 0; nt < 4; nt++) {
                const short8 bk0 = *(const short8*)&Ks[quad][nt * 16 + m][0];
                const short8 bk1 = *(const short8*)&Ks[4 + quad][nt * 16 + m][0];
                #pragma unroll
                for (int rt = 0; rt < 2; rt++) {
                    float4v s = {};
                    s = __builtin_amdgcn_mfma_f32_16x16x32_bf16(aq[rt][0], bk0, s, 0, 0, 0);
                    s = __builtin_amdgcn_mfma_f32_16x16x32_bf16(aq[rt][1], bk1, s, 0, 0, 0);
                    S[rt][nt] = s;
                }
            }

            // online softmax (rows live in lanes sharing `quad`; butterfly over 16)
            float alpha[2][4];
            #pragma unroll
            for (int rt = 0; rt < 2; rt++)
                #pragma unroll
                for (int r = 0; r < 4; r++) {
                    float x = fmaxf(fmaxf(S[rt][0][r], S[rt][1][r]),
                                    fmaxf(S[rt][2][r], S[rt][3][r]));
                    #pragma unroll
                    for (int off = 1; off < 16; off <<= 1)
                        x = fmaxf(x, __shfl_xor(x, off, 64));
                    const float mn = fmaxf(m_run[rt][r], x * c1);
                    alpha[rt][r] = exp2f(m_run[rt][r] - mn);
                    m_run[rt][r] = mn;
                }

            #pragma unroll
            for (int rt = 0; rt < 2; rt++) {
                float rs[4] = {0.f, 0.f, 0.f, 0.f};
                #pragma unroll
                for (int nt = 0; nt < 4; nt++) {
                    const int key = nt * 16 + m;
                    #pragma unroll
                    for (int r = 0; r < 4; r++) {
                        const float p = exp2f(fmaf(S[rt][nt][r], c1, -m_run[rt][r]));
                        rs[r] += p;
                        Ps[wave][key >> 3][rt * 16 + quad * 4 + r][key & 7] = f2bf(p);
                    }
                }
                #pragma unroll
                for (int r = 0; r < 4; r++) {
                    float x = rs[r];
                    #pragma unroll
                    for (int off = 1; off < 16; off <<= 1)
                        x += __shfl_xor(x, off, 64);
                    l_run[rt][r] = l_run[rt][r] * alpha[rt][r] + x;
                }
            }

            // O = O*alpha + P @ V
            #pragma unroll
            for (int rt = 0; rt < 2; rt++)
                #pragma unroll
                for (int ct = 0; ct < 4; ct++)
                    #pragma unroll
                    for (int r = 0; r < 4; r++)
                        O[rt][ct][r] *= alpha[rt][r];
            #pragma unroll
            for (int kk = 0; kk < 2; kk++) {
                short8 ap0 = *(const short8*)&Ps[wave][kk * 4 + quad][m][0];
                short8 ap1 = *(const short8*)&Ps[wave][kk * 4 + quad][16 + m][0];
                #pragma unroll
                for (int ct = 0; ct < 4; ct++) {
                    const short8 bv = *(const short8*)&Vt[kk * 4 + quad][ct * 16 + m][0];
                    O[0][ct] = __builtin_amdgcn_mfma_f32_16x16x32_bf16(ap0, bv, O[0][ct], 0, 0, 0);
                    O[1][ct] = __builtin_amdgcn_mfma_f32_16x16x32_bf16(ap1, bv, O[1][ct], 0, 0, 0);
                }
            }
        }
    }

    #pragma unroll
    for (int rt = 0; rt < 2; rt++) {
        float inv[4];
        #pragma unroll
        for (int r = 0; r < 4; r++)
            inv[r] = (l_run[rt][r] > 0.f) ? 1.f / l_run[rt][r] : 0.f;
        const size_t rowg = (size_t)((b * VDIM + v) * NDIM) + n0 + rt * 16 + quad * 4;
        #pragma unroll
        for (int ct = 0; ct < 4; ct++)
            #pragma unroll
            for (int r = 0; r < 4; r++)
                ctx[(rowg + r) * CDIM + h * DHE + ct * 16 + m] = O[rt][ct][r] * inv[r];
    }
}

// ---------------------------------------------------------------------------
// fp32 vector GEMM with has_ctx epilogue (round-1, known-good) for out-proj.
// ---------------------------------------------------------------------------
__global__ __launch_bounds__(256) void gemm_out_f32(
    const float* __restrict__ A, const float* __restrict__ W,
    const float* __restrict__ bias, float* __restrict__ out,
    const float* __restrict__ feats, const int* __restrict__ is_ref)
{
    __shared__ float As[16][68];
    __shared__ float Ws[16][68];
    const int t = threadIdx.x;
    const int tx = t & 15, ty = t >> 4;
    const int row0 = blockIdx.y * 64, col0 = blockIdx.x * 64;
    const int ar = t >> 2, ak = (t & 3) << 2;

    float acc[4][4] = {};
    for (int k0 = 0; k0 < CDIM; k0 += 16) {
        float4 av = *(const float4*)(A + (size_t)(row0 + ar) * CDIM + k0 + ak);
        float4 wv = *(const float4*)(W + (size_t)(col0 + ar) * CDIM + k0 + ak);
        As[ak + 0][ar] = av.x; As[ak + 1][ar] = av.y;
        As[ak + 2][ar] = av.z; As[ak + 3][ar] = av.w;
        Ws[ak + 0][ar] = wv.x; Ws[ak + 1][ar] = wv.y;
        Ws[ak + 2][ar] = wv.z; Ws[ak + 3][ar] = wv.w;
        __syncthreads();
        #pragma unroll
        for (int kk = 0; kk < 16; kk++) {
            float4 a4 = *(const float4*)&As[kk][ty << 2];
            float4 b4 = *(const float4*)&Ws[kk][tx << 2];
            float aa[4] = {a4.x, a4.y, a4.z, a4.w};
            float bb[4] = {b4.x, b4.y, b4.z, b4.w};
            #pragma unroll
            for (int i = 0; i < 4; i++)
                #pragma unroll
                for (int j = 0; j < 4; j++) acc[i][j] += aa[i] * bb[j];
        }
        __syncthreads();
    }

    float4 bv = *(const float4*)(bias + col0 + (tx << 2));
    const int bidx = row0 / (VDIM * NDIM);
    const int vidx = (row0 / NDIM) % VDIM;
    const int my = is_ref[bidx * VDIM + vidx];
    bool has = false;
    #pragma unroll
    for (int w = 0; w < VDIM; w++) has = has || (is_ref[bidx * VDIM + w] != my);
    #pragma unroll
    for (int i = 0; i < 4; i++) {
        const int r = row0 + (ty << 2) + i;
        float4 o;
        o.x = acc[i][0] + bv.x; o.y = acc[i][1] + bv.y;
        o.z = acc[i][2] + bv.z; o.w = acc[i][3] + bv.w;
        if (!has) o = *(const float4*)(feats + (size_t)r * CDIM + col0 + (tx << 2));
        *(float4*)(out + (size_t)r * CDIM + col0 + (tx << 2)) = o;
    }
}

extern "C" void kernel_launch(void* const* d_in, const int* in_sizes, int n_in,
                              void* d_out, int out_size, void* d_ws, size_t ws_size,
                              hipStream_t stream) {
    const float* feats = (const float*)d_in[0];
    const int*   is_ref = (const int*)d_in[1];
    const float* w_qkv = (const float*)d_in[2];
    const float* b_qkv = (const float*)d_in[3];
    const float* w_out = (const float*)d_in[4];
    const float* b_out = (const float*)d_in[5];
    float* out = (float*)d_out;

    unsigned short* feats_b = (unsigned short*)d_ws;               // 8192x768
    unsigned short* wqkv_b  = feats_b + (size_t)ROWS * CDIM;       // 2304x768
    unsigned short* qkv_b   = wqkv_b + (size_t)C3 * CDIM;          // 8192x2304
    float* ctx = (float*)(qkv_b + (size_t)ROWS * C3);              // 8192x768 fp32

    cast_bf16_kernel<<<4096, 256, 0, stream>>>(feats, feats_b, ROWS * CDIM / 4);
    cast_bf16_kernel<<<1728, 256, 0, stream>>>(w_qkv, wqkv_b, C3 * CDIM / 4);

    dim3 g1(C3 / 128, ROWS / 128);                                 // 18 x 64
    gemm_qkv_mfma<<<g1, 256, 0, stream>>>(feats_b, wqkv_b, b_qkv, qkv_b);

    dim3 g2(VDIM, HDIM, 2 * BDIM);                                 // 768 blocks
    attn_mfma<<<g2, 256, 0, stream>>>(qkv_b, is_ref, ctx);

    dim3 g3(CDIM / 64, ROWS / 64);                                 // 12 x 128
    gemm_out_f32<<<g3, 256, 0, stream>>>(ctx, w_out, b_out, out, feats, is_ref);
    (void)in_sizes; (void)n_in; (void)out_size; (void)ws_size;
}

// Round 3
// 396.104 us; speedup vs baseline: 3.8696x; 1.1258x over previous
//
#include <hip/hip_runtime.h>
#include <hip/hip_bf16.h>
#include <math.h>

#define BDIM 4
#define VDIM 8
#define NDIM 256
#define CDIM 768
#define HDIM 12
#define DHE  64
#define C3   (3*CDIM)
#define ROWS (BDIM*VDIM*NDIM)
#define KEYS (VDIM*NDIM)   // 2048

typedef __attribute__((ext_vector_type(8))) short short8;   // 8 bf16 = 4 VGPR
typedef __attribute__((ext_vector_type(4))) float float4v;  // MFMA acc

__device__ inline unsigned short f2bf(float f) {
    unsigned int u = __builtin_bit_cast(unsigned int, f);
    u += 0x7fffu + ((u >> 16) & 1u);   // RNE
    return (unsigned short)(u >> 16);
}

// ---------------------------------------------------------------------------
// fp32 -> bf16 cast, vectorized (n4 = #float4 groups)
// ---------------------------------------------------------------------------
__global__ void cast_bf16_kernel(const float* __restrict__ src,
                                 unsigned short* __restrict__ dst, int n4) {
    int i = blockIdx.x * blockDim.x + threadIdx.x;
    const int stride = gridDim.x * blockDim.x;
    for (; i < n4; i += stride) {
        float4 f = ((const float4*)src)[i];
        ushort4 o;
        o.x = f2bf(f.x); o.y = f2bf(f.y); o.z = f2bf(f.z); o.w = f2bf(f.w);
        ((ushort4*)dst)[i] = o;
    }
}

// ---------------------------------------------------------------------------
// bf16 MFMA GEMM for QKV proj (round-2, known-good).
// qkv[8192 x 2304] = feats_b @ w_qkv_b^T + bias, output bf16.
// ---------------------------------------------------------------------------
__global__ __launch_bounds__(256) void gemm_qkv_mfma(
    const unsigned short* __restrict__ A,   // [8192][768] bf16
    const unsigned short* __restrict__ W,   // [2304][768] bf16
    const float* __restrict__ bias,
    unsigned short* __restrict__ out)       // [8192][2304] bf16
{
    __shared__ unsigned short As[4][128][8];
    __shared__ unsigned short Ws[4][128][8];
    const int t = threadIdx.x;
    const int wave = t >> 6, lane = t & 63;
    const int m = lane & 15, quad = lane >> 4;
    const int wr = (wave >> 1) * 64, wc = (wave & 1) * 64;
    const int row0 = blockIdx.y * 128, col0 = blockIdx.x * 128;

    float4v acc[4][4] = {};

    for (int k0 = 0; k0 < CDIM; k0 += 32) {
        #pragma unroll
        for (int i = 0; i < 2; i++) {
            const int c = t + 256 * i;
            const int r = c >> 2, ko = (c & 3) << 3;
            *(uint4*)&As[ko >> 3][r][0] =
                *(const uint4*)&A[(size_t)(row0 + r) * CDIM + k0 + ko];
            *(uint4*)&Ws[ko >> 3][r][0] =
                *(const uint4*)&W[(size_t)(col0 + r) * CDIM + k0 + ko];
        }
        __syncthreads();
        short8 a[4], b[4];
        #pragma unroll
        for (int rt = 0; rt < 4; rt++) a[rt] = *(const short8*)&As[quad][wr + rt * 16 + m][0];
        #pragma unroll
        for (int ct = 0; ct < 4; ct++) b[ct] = *(const short8*)&Ws[quad][wc + ct * 16 + m][0];
        #pragma unroll
        for (int rt = 0; rt < 4; rt++)
            #pragma unroll
            for (int ct = 0; ct < 4; ct++)
                acc[rt][ct] = __builtin_amdgcn_mfma_f32_16x16x32_bf16(
                    a[rt], b[ct], acc[rt][ct], 0, 0, 0);
        __syncthreads();
    }

    #pragma unroll
    for (int ct = 0; ct < 4; ct++) {
        const int col = col0 + wc + ct * 16 + m;
        const float bv = bias[col];
        #pragma unroll
        for (int rt = 0; rt < 4; rt++) {
            const size_t row = (size_t)row0 + wr + rt * 16 + quad * 4;
            #pragma unroll
            for (int r = 0; r < 4; r++)
                out[(row + r) * C3 + col] = f2bf(acc[rt][ct][r] + bv);
        }
    }
}

// ---------------------------------------------------------------------------
// V transpose: qkv v-part [b][key 2048][h][64] -> vT [b][h][64][2048]
// so attention PV B-fragments are direct uint4 global loads.
// grid (32 key-tiles, 12, 4), 256 threads, 64x64 bf16 tile via LDS (pad 72).
// ---------------------------------------------------------------------------
__global__ __launch_bounds__(256) void transpose_v(
    const unsigned short* __restrict__ qkv, unsigned short* __restrict__ vT)
{
    __shared__ unsigned short T[64][72];
    const int kt = blockIdx.x, h = blockIdx.y, b = blockIdx.z;
    const int t = threadIdx.x;
    #pragma unroll
    for (int i = 0; i < 2; i++) {
        const int key = i * 32 + (t >> 3);
        const int dc = t & 7;
        const size_t row = (size_t)(b * KEYS + kt * 64 + key);
        *(uint4*)&T[key][dc * 8] =
            *(const uint4*)&qkv[row * C3 + 2 * CDIM + h * DHE + dc * 8];
    }
    __syncthreads();
    #pragma unroll
    for (int i = 0; i < 2; i++) {
        const int d = i * 32 + (t >> 3);
        const int kg = t & 7;
        unsigned short tmp[8];
        #pragma unroll
        for (int j = 0; j < 8; j++) tmp[j] = T[kg * 8 + j][d];
        *(uint4*)&vT[((size_t)((b * HDIM + h) * DHE + d)) * KEYS + kt * 64 + kg * 8] =
            *(uint4*)tmp;
    }
}

// ---------------------------------------------------------------------------
// Barrier-free MFMA flash attention.
// grid (V, H, 4*B) = 1536 blocks, 256 threads = 4 waves x 16 queries.
// K fragments load straight from qkv (natural layout == QK^T B-frag layout);
// V fragments load straight from vT. Only LDS use: wave-private Ps round-trip
// (P C-layout -> A-layout) with stride-72 rows + XOR block swizzle ->
// conflict-free. No __syncthreads anywhere.
// ---------------------------------------------------------------------------
__global__ __launch_bounds__(256, 4) void attn_mfma(
    const unsigned short* __restrict__ qkv,  // [8192][2304] bf16
    const unsigned short* __restrict__ vT,   // [4][12][64][2048] bf16
    const int* __restrict__ is_ref,
    unsigned short* __restrict__ ctx)        // [8192][768] bf16
{
    const int v = blockIdx.x, h = blockIdx.y;
    const int b = blockIdx.z >> 2, q4 = blockIdx.z & 3;
    const int t = threadIdx.x, wave = t >> 6, lane = t & 63;
    const int m = lane & 15, quad = lane >> 4;
    const int n0 = q4 * 64 + wave * 16;

    __shared__ unsigned short Ps[4][16][72];

    const int my_ref = is_ref[b * VDIM + v];
    const float c1 = 0.18033688f;  // 0.125 * log2(e)

    // Q A-frags: A[m=lane&15][k=quad*8+j], two 32-dim K-steps
    const size_t qrow = ((size_t)((b * VDIM + v) * NDIM + n0 + m)) * C3 + h * DHE;
    const short8 aq0 = *(const short8*)&qkv[qrow + quad * 8];
    const short8 aq1 = *(const short8*)&qkv[qrow + 32 + quad * 8];

    float m_run[4], l_run[4];
    float4v O[4] = {};
    #pragma unroll
    for (int r = 0; r < 4; r++) { m_run[r] = -1e30f; l_run[r] = 0.f; }

    const unsigned short* vTb = vT + (size_t)(b * HDIM + h) * DHE * KEYS;

    for (int w = 0; w < VDIM; w++) {
        if (((is_ref[b * VDIM + w] != 0) ^ (my_ref != 0)) == 0) continue;
        const unsigned short* kb =
            qkv + (size_t)((b * VDIM + w) * NDIM) * C3 + CDIM + h * DHE;
        const int key0 = w * NDIM;

        for (int m0 = 0; m0 < NDIM; m0 += 64) {
            // S = Q K^T : B-frag B[n=key][k=dim] direct from global
            float4v S[4];
            #pragma unroll
            for (int nt = 0; nt < 4; nt++) {
                const size_t kr = (size_t)(m0 + nt * 16 + m) * C3;
                const short8 bk0 = *(const short8*)&kb[kr + quad * 8];
                const short8 bk1 = *(const short8*)&kb[kr + 32 + quad * 8];
                float4v s = {};
                s = __builtin_amdgcn_mfma_f32_16x16x32_bf16(aq0, bk0, s, 0, 0, 0);
                s = __builtin_amdgcn_mfma_f32_16x16x32_bf16(aq1, bk1, s, 0, 0, 0);
                S[nt] = s;
            }

            // online softmax stats (rows = quad*4+r; keys across m-lanes x nt)
            float alpha[4];
            #pragma unroll
            for (int r = 0; r < 4; r++) {
                float x = fmaxf(fmaxf(S[0][r], S[1][r]), fmaxf(S[2][r], S[3][r]));
                #pragma unroll
                for (int off = 1; off < 16; off <<= 1)
                    x = fmaxf(x, __shfl_xor(x, off, 64));
                const float mn = fmaxf(m_run[r], x * c1);
                alpha[r] = exp2f(m_run[r] - mn);
                m_run[r] = mn;
            }

            // P = exp2(S*c1 - m); store to Ps in A-layout-readable swizzle
            float rs[4] = {0.f, 0.f, 0.f, 0.f};
            #pragma unroll
            for (int nt = 0; nt < 4; nt++) {
                const int cb = (2 * nt + (m >> 3)) ^ quad;   // swizzled col block
                #pragma unroll
                for (int r = 0; r < 4; r++) {
                    const float p = exp2f(fmaf(S[nt][r], c1, -m_run[r]));
                    rs[r] += p;
                    Ps[wave][quad * 4 + r][cb * 8 + (m & 7)] = f2bf(p);
                }
            }
            #pragma unroll
            for (int r = 0; r < 4; r++) {
                float x = rs[r];
                #pragma unroll
                for (int off = 1; off < 16; off <<= 1)
                    x += __shfl_xor(x, off, 64);
                l_run[r] = l_run[r] * alpha[r] + x;
            }

            // O = O*alpha + P @ V
            #pragma unroll
            for (int ct = 0; ct < 4; ct++)
                #pragma unroll
                for (int r = 0; r < 4; r++)
                    O[ct][r] *= alpha[r];
            #pragma unroll
            for (int kk = 0; kk < 2; kk++) {
                const int rb = (4 * kk + quad) ^ ((m >> 2) & 3);  // read swizzle
                const short8 ap = *(const short8*)&Ps[wave][m][rb * 8];
                #pragma unroll
                for (int ct = 0; ct < 4; ct++) {
                    const short8 bv = *(const short8*)&vTb[
                        (size_t)(ct * 16 + m) * KEYS + key0 + m0 + kk * 32 + quad * 8];
                    O[ct] = __builtin_amdgcn_mfma_f32_16x16x32_bf16(ap, bv, O[ct], 0, 0, 0);
                }
            }
        }
    }

    float inv[4];
    #pragma unroll
    for (int r = 0; r < 4; r++)
        inv[r] = (l_run[r] > 0.f) ? 1.f / l_run[r] : 0.f;
    const size_t rowg = (size_t)((b * VDIM + v) * NDIM) + n0 + quad * 4;
    #pragma unroll
    for (int ct = 0; ct < 4; ct++)
        #pragma unroll
        for (int r = 0; r < 4; r++)
            ctx[(rowg + r) * CDIM + h * DHE + ct * 16 + m] = f2bf(O[ct][r] * inv[r]);
}

// ---------------------------------------------------------------------------
// bf16 MFMA GEMM for out-proj: out[8192x768] = ctx_b @ w_out_b^T + bias,
// fp32 output, has_ctx/feats passthrough epilogue.
// ---------------------------------------------------------------------------
__global__ __launch_bounds__(256) void gemm_out_mfma(
    const unsigned short* __restrict__ A,   // ctx_b [8192][768]
    const unsigned short* __restrict__ W,   // wout_b [768][768]
    const float* __restrict__ bias,
    const float* __restrict__ feats,
    const int* __restrict__ is_ref,
    float* __restrict__ out)                // [8192][768] fp32
{
    __shared__ unsigned short As[4][128][8];
    __shared__ unsigned short Ws[4][128][8];
    const int t = threadIdx.x;
    const int wave = t >> 6, lane = t & 63;
    const int m = lane & 15, quad = lane >> 4;
    const int wr = (wave >> 1) * 64, wc = (wave & 1) * 64;
    const int row0 = blockIdx.y * 128, col0 = blockIdx.x * 128;

    float4v acc[4][4] = {};

    for (int k0 = 0; k0 < CDIM; k0 += 32) {
        #pragma unroll
        for (int i = 0; i < 2; i++) {
            const int c = t + 256 * i;
            const int r = c >> 2, ko = (c & 3) << 3;
            *(uint4*)&As[ko >> 3][r][0] =
                *(const uint4*)&A[(size_t)(row0 + r) * CDIM + k0 + ko];
            *(uint4*)&Ws[ko >> 3][r][0] =
                *(const uint4*)&W[(size_t)(col0 + r) * CDIM + k0 + ko];
        }
        __syncthreads();
        short8 a[4], b[4];
        #pragma unroll
        for (int rt = 0; rt < 4; rt++) a[rt] = *(const short8*)&As[quad][wr + rt * 16 + m][0];
        #pragma unroll
        for (int ct = 0; ct < 4; ct++) b[ct] = *(const short8*)&Ws[quad][wc + ct * 16 + m][0];
        #pragma unroll
        for (int rt = 0; rt < 4; rt++)
            #pragma unroll
            for (int ct = 0; ct < 4; ct++)
                acc[rt][ct] = __builtin_amdgcn_mfma_f32_16x16x32_bf16(
                    a[rt], b[ct], acc[rt][ct], 0, 0, 0);
        __syncthreads();
    }

    // per-block (b,v): 128 rows within one view (N=256 multiple of 128)
    const int bidx = row0 / (VDIM * NDIM);
    const int vidx = (row0 / NDIM) % VDIM;
    const int my = is_ref[bidx * VDIM + vidx];
    bool has = false;
    #pragma unroll
    for (int w = 0; w < VDIM; w++) has = has || (is_ref[bidx * VDIM + w] != my);

    #pragma unroll
    for (int ct = 0; ct < 4; ct++) {
        const int col = col0 + wc + ct * 16 + m;
        const float bv = bias[col];
        #pragma unroll
        for (int rt = 0; rt < 4; rt++) {
            const size_t row = (size_t)row0 + wr + rt * 16 + quad * 4;
            #pragma unroll
            for (int r = 0; r < 4; r++) {
                float o = acc[rt][ct][r] + bv;
                if (!has) o = feats[(row + r) * CDIM + col];
                out[(row + r) * CDIM + col] = o;
            }
        }
    }
}

extern "C" void kernel_launch(void* const* d_in, const int* in_sizes, int n_in,
                              void* d_out, int out_size, void* d_ws, size_t ws_size,
                              hipStream_t stream) {
    const float* feats = (const float*)d_in[0];
    const int*   is_ref = (const int*)d_in[1];
    const float* w_qkv = (const float*)d_in[2];
    const float* b_qkv = (const float*)d_in[3];
    const float* w_out = (const float*)d_in[4];
    const float* b_out = (const float*)d_in[5];
    float* out = (float*)d_out;

    unsigned short* feats_b = (unsigned short*)d_ws;            // 8192x768
    unsigned short* wqkv_b  = feats_b + (size_t)ROWS * CDIM;    // 2304x768
    unsigned short* wout_b  = wqkv_b + (size_t)C3 * CDIM;       // 768x768
    unsigned short* qkv_b   = wout_b + (size_t)CDIM * CDIM;     // 8192x2304
    unsigned short* vT      = qkv_b + (size_t)ROWS * C3;        // 4x12x64x2048
    unsigned short* ctx_b   = vT + (size_t)BDIM * HDIM * DHE * KEYS; // 8192x768

    cast_bf16_kernel<<<2048, 256, 0, stream>>>(feats, feats_b, ROWS * CDIM / 4);
    cast_bf16_kernel<<<1024, 256, 0, stream>>>(w_qkv, wqkv_b, C3 * CDIM / 4);
    cast_bf16_kernel<<<144, 256, 0, stream>>>(w_out, wout_b, CDIM * CDIM / 4);

    dim3 g1(C3 / 128, ROWS / 128);                              // 18 x 64
    gemm_qkv_mfma<<<g1, 256, 0, stream>>>(feats_b, wqkv_b, b_qkv, qkv_b);

    dim3 gt(KEYS / 64, HDIM, BDIM);                             // 32 x 12 x 4
    transpose_v<<<gt, 256, 0, stream>>>(qkv_b, vT);

    dim3 g2(VDIM, HDIM, 4 * BDIM);                              // 1536 blocks
    attn_mfma<<<g2, 256, 0, stream>>>(qkv_b, vT, is_ref, ctx_b);

    dim3 g3(CDIM / 128, ROWS / 128);                            // 6 x 64
    gemm_out_mfma<<<g3, 256, 0, stream>>>(ctx_b, wout_b, b_out, feats, is_ref, out);
    (void)in_sizes; (void)n_in; (void)out_size; (void)ws_size;
}

// Round 5
// 300.152 us; speedup vs baseline: 5.1066x; 1.3197x over previous
//
#include <hip/hip_runtime.h>
#include <hip/hip_bf16.h>
#include <math.h>

#define BDIM 4
#define VDIM 8
#define NDIM 256
#define CDIM 768
#define HDIM 12
#define DHE  64
#define C3   (3*CDIM)
#define ROWS (BDIM*VDIM*NDIM)
#define KEYS (VDIM*NDIM)   // 2048

typedef __attribute__((ext_vector_type(8))) short short8;   // 8 bf16 = 4 VGPR
typedef __attribute__((ext_vector_type(4))) float float4v;  // MFMA acc

__device__ inline unsigned short f2bf(float f) {
    unsigned int u = __builtin_bit_cast(unsigned int, f);
    u += 0x7fffu + ((u >> 16) & 1u);   // RNE
    return (unsigned short)(u >> 16);
}

// ---------------------------------------------------------------------------
// fp32 -> bf16 cast, vectorized (n4 = #float4 groups)
// ---------------------------------------------------------------------------
__global__ void cast_bf16_kernel(const float* __restrict__ src,
                                 unsigned short* __restrict__ dst, int n4) {
    int i = blockIdx.x * blockDim.x + threadIdx.x;
    const int stride = gridDim.x * blockDim.x;
    for (; i < n4; i += stride) {
        float4 f = ((const float4*)src)[i];
        ushort4 o;
        o.x = f2bf(f.x); o.y = f2bf(f.y); o.z = f2bf(f.z); o.w = f2bf(f.w);
        ((ushort4*)dst)[i] = o;
    }
}

// ---------------------------------------------------------------------------
// bf16 MFMA GEMM for QKV proj (round-2, known-good).
// ---------------------------------------------------------------------------
__global__ __launch_bounds__(256) void gemm_qkv_mfma(
    const unsigned short* __restrict__ A,   // [8192][768] bf16
    const unsigned short* __restrict__ W,   // [2304][768] bf16
    const float* __restrict__ bias,
    unsigned short* __restrict__ out)       // [8192][2304] bf16
{
    __shared__ unsigned short As[4][128][8];
    __shared__ unsigned short Ws[4][128][8];
    const int t = threadIdx.x;
    const int wave = t >> 6, lane = t & 63;
    const int m = lane & 15, quad = lane >> 4;
    const int wr = (wave >> 1) * 64, wc = (wave & 1) * 64;
    const int row0 = blockIdx.y * 128, col0 = blockIdx.x * 128;

    float4v acc[4][4] = {};

    for (int k0 = 0; k0 < CDIM; k0 += 32) {
        #pragma unroll
        for (int i = 0; i < 2; i++) {
            const int c = t + 256 * i;
            const int r = c >> 2, ko = (c & 3) << 3;
            *(uint4*)&As[ko >> 3][r][0] =
                *(const uint4*)&A[(size_t)(row0 + r) * CDIM + k0 + ko];
            *(uint4*)&Ws[ko >> 3][r][0] =
                *(const uint4*)&W[(size_t)(col0 + r) * CDIM + k0 + ko];
        }
        __syncthreads();
        short8 a[4], b[4];
        #pragma unroll
        for (int rt = 0; rt < 4; rt++) a[rt] = *(const short8*)&As[quad][wr + rt * 16 + m][0];
        #pragma unroll
        for (int ct = 0; ct < 4; ct++) b[ct] = *(const short8*)&Ws[quad][wc + ct * 16 + m][0];
        #pragma unroll
        for (int rt = 0; rt < 4; rt++)
            #pragma unroll
            for (int ct = 0; ct < 4; ct++)
                acc[rt][ct] = __builtin_amdgcn_mfma_f32_16x16x32_bf16(
                    a[rt], b[ct], acc[rt][ct], 0, 0, 0);
        __syncthreads();
    }

    #pragma unroll
    for (int ct = 0; ct < 4; ct++) {
        const int col = col0 + wc + ct * 16 + m;
        const float bv = bias[col];
        #pragma unroll
        for (int rt = 0; rt < 4; rt++) {
            const size_t row = (size_t)row0 + wr + rt * 16 + quad * 4;
            #pragma unroll
            for (int r = 0; r < 4; r++)
                out[(row + r) * C3 + col] = f2bf(acc[rt][ct][r] + bv);
        }
    }
}

// ---------------------------------------------------------------------------
// V transpose: qkv v-part [b][key 2048][h][64] -> vT [b][h][64][2048]
// ---------------------------------------------------------------------------
__global__ __launch_bounds__(256) void transpose_v(
    const unsigned short* __restrict__ qkv, unsigned short* __restrict__ vT)
{
    __shared__ unsigned short T[64][72];
    const int kt = blockIdx.x, h = blockIdx.y, b = blockIdx.z;
    const int t = threadIdx.x;
    #pragma unroll
    for (int i = 0; i < 2; i++) {
        const int key = i * 32 + (t >> 3);
        const int dc = t & 7;
        const size_t row = (size_t)(b * KEYS + kt * 64 + key);
        *(uint4*)&T[key][dc * 8] =
            *(const uint4*)&qkv[row * C3 + 2 * CDIM + h * DHE + dc * 8];
    }
    __syncthreads();
    #pragma unroll
    for (int i = 0; i < 2; i++) {
        const int d = i * 32 + (t >> 3);
        const int kg = t & 7;
        unsigned short tmp[8];
        #pragma unroll
        for (int j = 0; j < 8; j++) tmp[j] = T[kg * 8 + j][d];
        *(uint4*)&vT[((size_t)((b * HDIM + h) * DHE + d)) * KEYS + kt * 64 + kg * 8] =
            *(uint4*)tmp;
    }
}

// ---------------------------------------------------------------------------
// MFMA flash attention, round 5 (round-4 structure + Ps overflow fix).
// grid (V, H, 2B) = 768 blocks = 3/CU; 4 waves x 32 queries = 128 q/block.
// 128-key chunks staged in LDS (XOR-swizzled, conflict-free); global->reg
// prefetch of chunk i+1 between the two barriers of chunk i.
// Fixed-offset softmax (M0=0), exact by shift-invariance; scores ~|0.3|
// in exp2 domain, no overflow risk.
// P is processed in two 64-key halves through Ps[32][72] (col = nt4*16+m
// <= 63 < 72 -- R4 bug was 128-wide writes into this 72-stride buffer).
// Wave-private Ps + in-order DS pipe => no barrier between halves.
// ---------------------------------------------------------------------------
__global__ __launch_bounds__(256, 3) void attn_mfma(
    const unsigned short* __restrict__ qkv,  // [8192][2304] bf16
    const unsigned short* __restrict__ vT,   // [4][12][64][2048] bf16
    const int* __restrict__ is_ref,
    unsigned short* __restrict__ ctx)        // [8192][768] bf16
{
    const int v = blockIdx.x, h = blockIdx.y;
    const int b = blockIdx.z >> 1, half = blockIdx.z & 1;
    const int t = threadIdx.x, wave = t >> 6, lane = t & 63;
    const int m = lane & 15, quad = lane >> 4;
    const int n0 = half * 128 + wave * 32;

    __shared__ unsigned short Ks[128][64];   // [key][dim], dg' = dg ^ (key&7)
    __shared__ unsigned short Vs[64][128];   // [dim][key], kg' = kg ^ (dim&15)
    __shared__ unsigned short Ps[4][32][72]; // [wave][query][64-key half]

    const int my_ref = is_ref[b * VDIM + v];
    unsigned amask = 0;
    #pragma unroll
    for (int w = 0; w < VDIM; w++)
        if ((is_ref[b * VDIM + w] != 0) ^ (my_ref != 0)) amask |= 1u << w;
    const int nChunks = 2 * __popc(amask);

    const float c1 = 0.18033688f;  // 0.125 * log2(e)

    // Q A-frags: A[m][k=quad*8+j], two 32-dim K-steps
    short8 aq[2][2];
    #pragma unroll
    for (int rt = 0; rt < 2; rt++) {
        const size_t row = (size_t)((b * VDIM + v) * NDIM) + n0 + rt * 16 + m;
        #pragma unroll
        for (int ks = 0; ks < 2; ks++)
            aq[rt][ks] = *(const short8*)&qkv[row * C3 + h * DHE + ks * 32 + quad * 8];
    }

    float rs[2][4] = {};
    float4v O[2][4] = {};

    // staging thread coords
    const int k_key = t >> 3, k_dg = t & 7;    // key = i*32 + k_key
    const int v_dim = t >> 4, v_kg = t & 15;   // dim = i*16 + v_dim

    const unsigned short* vTb = vT + (size_t)(b * HDIM + h) * DHE * KEYS;

    uint4 kreg[4], vreg[4];
    unsigned rem = amask;
    int wcur = __builtin_ffs((int)rem) - 1;

    if (nChunks > 0) {
        const unsigned short* kb =
            qkv + (size_t)((b * VDIM + wcur) * NDIM) * C3 + CDIM + h * DHE;
        #pragma unroll
        for (int i = 0; i < 4; i++)
            kreg[i] = *(const uint4*)&kb[(size_t)(i * 32 + k_key) * C3 + k_dg * 8];
        #pragma unroll
        for (int i = 0; i < 4; i++)
            vreg[i] = *(const uint4*)&vTb[(size_t)(i * 16 + v_dim) * KEYS
                                          + wcur * NDIM + v_kg * 8];
    }

    for (int ci = 0; ci < nChunks; ci++) {
        __syncthreads();   // prev chunk's LDS reads complete
        #pragma unroll
        for (int i = 0; i < 4; i++)
            *(uint4*)&Ks[i * 32 + k_key][(k_dg ^ (k_key & 7)) * 8] = kreg[i];
        #pragma unroll
        for (int i = 0; i < 4; i++)
            *(uint4*)&Vs[i * 16 + v_dim][(v_kg ^ v_dim) * 8] = vreg[i];

        if (ci + 1 < nChunks) {   // prefetch next chunk into regs
            int wn, m0n;
            if ((ci & 1) == 0) { wn = wcur; m0n = 128; }
            else {
                unsigned r2 = rem & (rem - 1);
                wn = __builtin_ffs((int)r2) - 1; m0n = 0;
            }
            const unsigned short* kb =
                qkv + (size_t)((b * VDIM + wn) * NDIM + m0n) * C3 + CDIM + h * DHE;
            #pragma unroll
            for (int i = 0; i < 4; i++)
                kreg[i] = *(const uint4*)&kb[(size_t)(i * 32 + k_key) * C3 + k_dg * 8];
            #pragma unroll
            for (int i = 0; i < 4; i++)
                vreg[i] = *(const uint4*)&vTb[(size_t)(i * 16 + v_dim) * KEYS
                                              + wn * NDIM + m0n + v_kg * 8];
        }
        __syncthreads();   // LDS tiles visible

        // two 64-key halves: S-tiles -> Ps, then PV for that half
        #pragma unroll
        for (int hk = 0; hk < 2; hk++) {
            #pragma unroll
            for (int nt4 = 0; nt4 < 4; nt4++) {
                const int nt = hk * 4 + nt4;
                const short8 bk0 = *(const short8*)&Ks[nt * 16 + m][(quad ^ (m & 7)) * 8];
                const short8 bk1 = *(const short8*)&Ks[nt * 16 + m][((4 + quad) ^ (m & 7)) * 8];
                #pragma unroll
                for (int rt = 0; rt < 2; rt++) {
                    float4v s = {};
                    s = __builtin_amdgcn_mfma_f32_16x16x32_bf16(aq[rt][0], bk0, s, 0, 0, 0);
                    s = __builtin_amdgcn_mfma_f32_16x16x32_bf16(aq[rt][1], bk1, s, 0, 0, 0);
                    #pragma unroll
                    for (int r = 0; r < 4; r++) {
                        const float p = __builtin_amdgcn_exp2f(s[r] * c1);
                        rs[rt][r] += p;
                        Ps[wave][rt * 16 + quad * 4 + r][nt4 * 16 + m] = f2bf(p);
                    }
                }
            }
            #pragma unroll
            for (int kk = 0; kk < 2; kk++) {
                const short8 ap0 = *(const short8*)&Ps[wave][m][kk * 32 + quad * 8];
                const short8 ap1 = *(const short8*)&Ps[wave][16 + m][kk * 32 + quad * 8];
                #pragma unroll
                for (int ct = 0; ct < 4; ct++) {
                    const short8 bv = *(const short8*)&Vs[ct * 16 + m]
                        [((hk * 8 + kk * 4 + quad) ^ m) * 8];
                    O[0][ct] = __builtin_amdgcn_mfma_f32_16x16x32_bf16(ap0, bv, O[0][ct], 0, 0, 0);
                    O[1][ct] = __builtin_amdgcn_mfma_f32_16x16x32_bf16(ap1, bv, O[1][ct], 0, 0, 0);
                }
            }
        }
        if (ci & 1) { rem &= rem - 1; wcur = __builtin_ffs((int)rem) - 1; }
    }

    // final: reduce l over the 16 m-lanes, normalize, write
    #pragma unroll
    for (int rt = 0; rt < 2; rt++) {
        float inv[4];
        #pragma unroll
        for (int r = 0; r < 4; r++) {
            float x = rs[rt][r];
            #pragma unroll
            for (int off = 1; off < 16; off <<= 1)
                x += __shfl_xor(x, off, 64);
            inv[r] = (x > 0.f) ? 1.f / x : 0.f;
        }
        const size_t rowg = (size_t)((b * VDIM + v) * NDIM) + n0 + rt * 16 + quad * 4;
        #pragma unroll
        for (int ct = 0; ct < 4; ct++)
            #pragma unroll
            for (int r = 0; r < 4; r++)
                ctx[(rowg + r) * CDIM + h * DHE + ct * 16 + m] = f2bf(O[rt][ct][r] * inv[r]);
    }
}

// ---------------------------------------------------------------------------
// bf16 MFMA GEMM for out-proj (round-3, known-good).
// ---------------------------------------------------------------------------
__global__ __launch_bounds__(256) void gemm_out_mfma(
    const unsigned short* __restrict__ A,   // ctx_b [8192][768]
    const unsigned short* __restrict__ W,   // wout_b [768][768]
    const float* __restrict__ bias,
    const float* __restrict__ feats,
    const int* __restrict__ is_ref,
    float* __restrict__ out)                // [8192][768] fp32
{
    __shared__ unsigned short As[4][128][8];
    __shared__ unsigned short Ws[4][128][8];
    const int t = threadIdx.x;
    const int wave = t >> 6, lane = t & 63;
    const int m = lane & 15, quad = lane >> 4;
    const int wr = (wave >> 1) * 64, wc = (wave & 1) * 64;
    const int row0 = blockIdx.y * 128, col0 = blockIdx.x * 128;

    float4v acc[4][4] = {};

    for (int k0 = 0; k0 < CDIM; k0 += 32) {
        #pragma unroll
        for (int i = 0; i < 2; i++) {
            const int c = t + 256 * i;
            const int r = c >> 2, ko = (c & 3) << 3;
            *(uint4*)&As[ko >> 3][r][0] =
                *(const uint4*)&A[(size_t)(row0 + r) * CDIM + k0 + ko];
            *(uint4*)&Ws[ko >> 3][r][0] =
                *(const uint4*)&W[(size_t)(col0 + r) * CDIM + k0 + ko];
        }
        __syncthreads();
        short8 a[4], b[4];
        #pragma unroll
        for (int rt = 0; rt < 4; rt++) a[rt] = *(const short8*)&As[quad][wr + rt * 16 + m][0];
        #pragma unroll
        for (int ct = 0; ct < 4; ct++) b[ct] = *(const short8*)&Ws[quad][wc + ct * 16 + m][0];
        #pragma unroll
        for (int rt = 0; rt < 4; rt++)
            #pragma unroll
            for (int ct = 0; ct < 4; ct++)
                acc[rt][ct] = __builtin_amdgcn_mfma_f32_16x16x32_bf16(
                    a[rt], b[ct], acc[rt][ct], 0, 0, 0);
        __syncthreads();
    }

    const int bidx = row0 / (VDIM * NDIM);
    const int vidx = (row0 / NDIM) % VDIM;
    const int my = is_ref[bidx * VDIM + vidx];
    bool has = false;
    #pragma unroll
    for (int w = 0; w < VDIM; w++) has = has || (is_ref[bidx * VDIM + w] != my);

    #pragma unroll
    for (int ct = 0; ct < 4; ct++) {
        const int col = col0 + wc + ct * 16 + m;
        const float bv = bias[col];
        #pragma unroll
        for (int rt = 0; rt < 4; rt++) {
            const size_t row = (size_t)row0 + wr + rt * 16 + quad * 4;
            #pragma unroll
            for (int r = 0; r < 4; r++) {
                float o = acc[rt][ct][r] + bv;
                if (!has) o = feats[(row + r) * CDIM + col];
                out[(row + r) * CDIM + col] = o;
            }
        }
    }
}

extern "C" void kernel_launch(void* const* d_in, const int* in_sizes, int n_in,
                              void* d_out, int out_size, void* d_ws, size_t ws_size,
                              hipStream_t stream) {
    const float* feats = (const float*)d_in[0];
    const int*   is_ref = (const int*)d_in[1];
    const float* w_qkv = (const float*)d_in[2];
    const float* b_qkv = (const float*)d_in[3];
    const float* w_out = (const float*)d_in[4];
    const float* b_out = (const float*)d_in[5];
    float* out = (float*)d_out;

    unsigned short* feats_b = (unsigned short*)d_ws;            // 8192x768
    unsigned short* wqkv_b  = feats_b + (size_t)ROWS * CDIM;    // 2304x768
    unsigned short* wout_b  = wqkv_b + (size_t)C3 * CDIM;       // 768x768
    unsigned short* qkv_b   = wout_b + (size_t)CDIM * CDIM;     // 8192x2304
    unsigned short* vT      = qkv_b + (size_t)ROWS * C3;        // 4x12x64x2048
    unsigned short* ctx_b   = vT + (size_t)BDIM * HDIM * DHE * KEYS; // 8192x768

    cast_bf16_kernel<<<2048, 256, 0, stream>>>(feats, feats_b, ROWS * CDIM / 4);
    cast_bf16_kernel<<<1024, 256, 0, stream>>>(w_qkv, wqkv_b, C3 * CDIM / 4);
    cast_bf16_kernel<<<144, 256, 0, stream>>>(w_out, wout_b, CDIM * CDIM / 4);

    dim3 g1(C3 / 128, ROWS / 128);                              // 18 x 64
    gemm_qkv_mfma<<<g1, 256, 0, stream>>>(feats_b, wqkv_b, b_qkv, qkv_b);

    dim3 gt(KEYS / 64, HDIM, BDIM);                             // 32 x 12 x 4
    transpose_v<<<gt, 256, 0, stream>>>(qkv_b, vT);

    dim3 g2(VDIM, HDIM, 2 * BDIM);                              // 768 blocks
    attn_mfma<<<g2, 256, 0, stream>>>(qkv_b, vT, is_ref, ctx_b);

    dim3 g3(CDIM / 128, ROWS / 128);                            // 6 x 64
    gemm_out_mfma<<<g3, 256, 0, stream>>>(ctx_b, wout_b, b_out, feats, is_ref, out);
    (void)in_sizes; (void)n_in; (void)out_size; (void)ws_size;
}